// Round 1
// baseline (9721.799 us; speedup 1.0000x reference)
//
#include <hip/hip_runtime.h>
#include <hip/hip_bf16.h>
#include <stdint.h>

// ---------------------------------------------------------------------------
// ConvLSTM (GRU-style) T=512 B=64 D=1024 H=1024.
// Plan: xall = [X@Wzx^T, X@Wrx^T, X@Wcx^T]  (big parallel GEMM, bf16)
//       then cooperative recurrent kernel: 512 steps, 2 device barriers/step.
// ---------------------------------------------------------------------------

typedef float  f32x4  __attribute__((ext_vector_type(4)));
typedef __bf16 bf16x8 __attribute__((ext_vector_type(8)));

#define NWG 128          // recurrent workgroups
#define TSTEPS 512
#define BATCH 64

// ws layout (bytes)
#define XALL_OFF 0UL
#define XALL_BYTES (32768UL * 3072UL * 2UL)            // 201326592
#define WXP_OFF  (XALL_OFF + XALL_BYTES)               // 201326592
#define WXP_BYTES (3072UL * 1024UL * 2UL)              // 6291456
#define HBF_OFF  (WXP_OFF + WXP_BYTES)                 // 207618048
#define RH_OFF   (HBF_OFF + 131072UL)                  // 207749120
#define BAR_OFF  (RH_OFF + 131072UL)                   // 207880192
#define WS_NEED  (BAR_OFF + 4096UL)

#define GL_LDS16(g, l) __builtin_amdgcn_global_load_lds( \
    (const __attribute__((address_space(1))) void*)(const void*)(g), \
    (__attribute__((address_space(3))) void*)(void*)(l), 16, 0, 0)

__device__ __forceinline__ unsigned short f2bf(float f) {
  __hip_bfloat16 h = __float2bfloat16(f);
  return __builtin_bit_cast(unsigned short, h);
}
__device__ __forceinline__ bf16x8 ld16(const void* p) {
  return __builtin_bit_cast(bf16x8, *(const uint4*)p);
}
__device__ __forceinline__ f32x4 mfma16(bf16x8 a, bf16x8 b, f32x4 c) {
  return __builtin_amdgcn_mfma_f32_16x16x32_bf16(a, b, c, 0, 0, 0);
}
__device__ __forceinline__ float sigm(float x) {
  return __builtin_amdgcn_rcpf(1.0f + __builtin_amdgcn_exp2f(-1.4426950408889634f * x));
}
__device__ __forceinline__ float tanh_fast(float x) {
  return 1.0f - 2.0f * __builtin_amdgcn_rcpf(1.0f + __builtin_amdgcn_exp2f(2.8853900817779268f * x));
}

// --------------------------- prep kernels ----------------------------------
__global__ void cvt_x(const float* __restrict__ x, __hip_bfloat16* __restrict__ o) {
  size_t i = ((size_t)blockIdx.x * 256 + threadIdx.x) * 4;
  float4 v = *(const float4*)(x + i);
  ushort4 u; u.x = f2bf(v.x); u.y = f2bf(v.y); u.z = f2bf(v.z); u.w = f2bf(v.w);
  *(ushort4*)(o + i) = u;
}

// Wxp[row][k] = x-part (cols 0..1023) of Wfc row (row<2048) or Wfc2 row-2048
__global__ void pack_w(const float* __restrict__ Wfc, const float* __restrict__ Wfc2,
                       __hip_bfloat16* __restrict__ Wxp) {
  int row = blockIdx.x;
  int k = threadIdx.x * 4;
  const float* src = (row < 2048) ? (Wfc + (size_t)row * 2048 + k)
                                  : (Wfc2 + (size_t)(row - 2048) * 2048 + k);
  float4 v = *(const float4*)src;
  ushort4 u; u.x = f2bf(v.x); u.y = f2bf(v.y); u.z = f2bf(v.z); u.w = f2bf(v.w);
  *(ushort4*)(Wxp + (size_t)row * 1024 + k) = u;
}

__global__ void init_k(__hip_bfloat16* __restrict__ hbf, int* __restrict__ bar) {
  size_t i = ((size_t)blockIdx.x * 256 + threadIdx.x) * 4;
  unsigned short hv = f2bf(1e-9f);
  ushort4 u; u.x = hv; u.y = hv; u.z = hv; u.w = hv;
  *(ushort4*)(hbf + i) = u;
  if (blockIdx.x == 0) {
    int4 z; z.x = 0; z.y = 0; z.z = 0; z.w = 0;
    ((int4*)bar)[threadIdx.x] = z;
  }
}

// --------------------------- precompute GEMM -------------------------------
// C[32768,3072] = A[32768,1024] @ B[3072,1024]^T   (all bf16, fp32 acc)
__global__ void __launch_bounds__(256) gemm_xw(const __hip_bfloat16* __restrict__ A,
                                               const __hip_bfloat16* __restrict__ B,
                                               __hip_bfloat16* __restrict__ C) {
  __shared__ __hip_bfloat16 As[128 * 64];
  __shared__ __hip_bfloat16 Bs[128 * 64];
  const int tid = threadIdx.x, lane = tid & 63, wv = tid >> 6;
  const int bn = blockIdx.x, bm = blockIdx.y;
  const int wm = wv >> 1, wn = wv & 1;
  const int n = lane & 15, q = lane >> 4;
  f32x4 acc[4][4];
#pragma unroll
  for (int i = 0; i < 4; ++i)
#pragma unroll
    for (int j = 0; j < 4; ++j) acc[i][j] = (f32x4){0.f, 0.f, 0.f, 0.f};
  const __hip_bfloat16* Ab = A + (size_t)bm * 128 * 1024;
  const __hip_bfloat16* Bb = B + (size_t)bn * 128 * 1024;
  for (int ko = 0; ko < 1024; ko += 64) {
#pragma unroll
    for (int r = 0; r < 4; ++r) {
      int chunk = r * 256 + wv * 64 + lane;
      int row = chunk >> 3, c16 = chunk & 7;
      GL_LDS16(Ab + (size_t)row * 1024 + ko + c16 * 8, (char*)As + (r * 256 + wv * 64) * 16);
      GL_LDS16(Bb + (size_t)row * 1024 + ko + c16 * 8, (char*)Bs + (r * 256 + wv * 64) * 16);
    }
    __syncthreads();
#pragma unroll
    for (int ks = 0; ks < 2; ++ks) {
      bf16x8 af[4], bfr[4];
#pragma unroll
      for (int mi = 0; mi < 4; ++mi)
        af[mi] = ld16((const char*)As + (wm * 64 + mi * 16 + n) * 128 + ks * 64 + q * 16);
#pragma unroll
      for (int ni = 0; ni < 4; ++ni)
        bfr[ni] = ld16((const char*)Bs + (wn * 64 + ni * 16 + n) * 128 + ks * 64 + q * 16);
#pragma unroll
      for (int mi = 0; mi < 4; ++mi)
#pragma unroll
        for (int ni = 0; ni < 4; ++ni)
          acc[mi][ni] = mfma16(af[mi], bfr[ni], acc[mi][ni]);
    }
    __syncthreads();
  }
#pragma unroll
  for (int mi = 0; mi < 4; ++mi)
#pragma unroll
    for (int ni = 0; ni < 4; ++ni) {
      int col = bn * 128 + wn * 64 + ni * 16 + n;
#pragma unroll
      for (int r = 0; r < 4; ++r) {
        int row = bm * 128 + wm * 64 + mi * 16 + q * 4 + r;
        C[(size_t)row * 3072 + col] = __float2bfloat16(acc[mi][ni][r]);
      }
    }
}

// --------------------------- device barrier --------------------------------
__device__ __forceinline__ void grid_bar(int* cnt, int* rel, int bi, int g) {
  __syncthreads();
  if (threadIdx.x == 0) {
    __hip_atomic_fetch_add(&cnt[(g & 7) << 5], 1, __ATOMIC_RELEASE, __HIP_MEMORY_SCOPE_AGENT);
    if (g == 0) {
      const int target = NWG * (bi + 1);
      for (;;) {
        int s = 0;
#pragma unroll
        for (int i = 0; i < 8; ++i)
          s += __hip_atomic_load(&cnt[i << 5], __ATOMIC_RELAXED, __HIP_MEMORY_SCOPE_AGENT);
        if (s >= target) break;
      }
      __hip_atomic_store(rel, bi + 1, __ATOMIC_RELEASE, __HIP_MEMORY_SCOPE_AGENT);
      (void)__hip_atomic_load(rel, __ATOMIC_ACQUIRE, __HIP_MEMORY_SCOPE_AGENT);
    } else {
      while (__hip_atomic_load(rel, __ATOMIC_RELAXED, __HIP_MEMORY_SCOPE_AGENT) < bi + 1) {}
      (void)__hip_atomic_load(rel, __ATOMIC_ACQUIRE, __HIP_MEMORY_SCOPE_AGENT);
    }
  }
  __syncthreads();
}

// --------------------------- recurrent kernel ------------------------------
// 128 WGs x 256 thr. WG g owns h columns [g*8, g*8+8).
// LDS W1s rows 0..7 = Wfc rows g*8+j (z), rows 8..15 = Wfc rows 1024+g*8+j (r),
// W2s rows 0..7 = Wfc2 rows g*8+j; all h-part (cols 1024..2048), bf16, XOR-swizzled.
__global__ void __launch_bounds__(256, 1) recurrent_k(
    const float* __restrict__ Wfc, const float* __restrict__ Wfc2,
    const __hip_bfloat16* __restrict__ xall,
    __hip_bfloat16* __restrict__ hbf,
    __hip_bfloat16* __restrict__ rhb,
    float* __restrict__ out,
    int* __restrict__ bar) {
  __shared__ __hip_bfloat16 W1s[16 * 1024];
  __shared__ __hip_bfloat16 W2s[8 * 1024];
  const int g = blockIdx.x, tid = threadIdx.x;
  const int lane = tid & 63, wv = tid >> 6;
  const int n = lane & 15, q = lane >> 4;
  int* cnt = bar;
  int* rel = bar + 256;

  {  // one-time weight load to LDS (swizzled: byte ^= (row&7)<<4)
    const int k0 = tid * 4;
    for (int j = 0; j < 16; ++j) {
      int grow = (j < 8) ? (g * 8 + j) : (1024 + g * 8 + (j - 8));
      float4 v = *(const float4*)(Wfc + (size_t)grow * 2048 + 1024 + k0);
      ushort4 u; u.x = f2bf(v.x); u.y = f2bf(v.y); u.z = f2bf(v.z); u.w = f2bf(v.w);
      *(ushort4*)((char*)W1s + j * 2048 + ((k0 * 2) ^ ((j & 7) << 4))) = u;
    }
    for (int j = 0; j < 8; ++j) {
      int grow = g * 8 + j;
      float4 v = *(const float4*)(Wfc2 + (size_t)grow * 2048 + 1024 + k0);
      ushort4 u; u.x = f2bf(v.x); u.y = f2bf(v.y); u.z = f2bf(v.z); u.w = f2bf(v.w);
      *(ushort4*)((char*)W2s + j * 2048 + ((k0 * 2) ^ ((j & 7) << 4))) = u;
    }
  }
  __syncthreads();

  const int m0 = wv * 16 + q * 4;        // C rows for this lane: m0..m0+3
  const int arow = wv * 16 + n;          // A-fragment row
  const int jcol = g * 8 + (n & 7);      // h column this lane owns/serves
  const int xcol1 = (n < 8) ? (g * 8 + n) : (1024 + g * 8 + (n - 8));
  const int xcol2 = 2048 + g * 8 + (n & 7);
  const char* hApt = (const char*)hbf + arow * 2048 + q * 16;
  const char* rApt = (const char*)rhb + arow * 2048 + q * 16;
  const char* w1b = (const char*)W1s + n * 2048;
  const char* w2b = (const char*)W2s + (n & 7) * 2048;
  const int sw = (n & 7) << 4;

  float hf[4] = {1e-9f, 1e-9f, 1e-9f, 1e-9f};
  int bi = 0;

  for (int t = 0; t < TSTEPS; ++t) {
    const __hip_bfloat16* xr = xall + (size_t)t * 64 * 3072;
    float xv[4], x2[4];
#pragma unroll
    for (int r = 0; r < 4; ++r) {
      xv[r] = __bfloat162float(xr[(m0 + r) * 3072 + xcol1]);
      x2[r] = __bfloat162float(xr[(m0 + r) * 3072 + xcol2]);
    }
    // ---- phase 1: cc = h @ W1^T (+x part), z/r ----
    f32x4 a0 = (f32x4){0.f, 0.f, 0.f, 0.f}, a1 = (f32x4){0.f, 0.f, 0.f, 0.f};
#pragma unroll
    for (int ks = 0; ks < 32; ks += 2) {
      a0 = mfma16(ld16(hApt + ks * 64), ld16(w1b + ((ks * 64 + q * 16) ^ sw)), a0);
      a1 = mfma16(ld16(hApt + ks * 64 + 64), ld16(w1b + ((ks * 64 + 64 + q * 16) ^ sw)), a1);
    }
    f32x4 cc = a0 + a1;
    float zz[4], hsh[4];
#pragma unroll
    for (int r = 0; r < 4; ++r) hsh[r] = __shfl_xor(hf[r], 8);
#pragma unroll
    for (int r = 0; r < 4; ++r) {
      float s = sigm(cc[r] + xv[r]);
      if (n < 8) {
        zz[r] = s;
      } else {
        rhb[(m0 + r) * 1024 + jcol] = __float2bfloat16(s * hsh[r]);
      }
    }
    grid_bar(cnt, rel, bi++, g);
    // ---- phase 2: con2 = (r*h) @ W2^T (+x part), h update ----
    f32x4 b0 = (f32x4){0.f, 0.f, 0.f, 0.f}, b1 = (f32x4){0.f, 0.f, 0.f, 0.f};
#pragma unroll
    for (int ks = 0; ks < 32; ks += 2) {
      b0 = mfma16(ld16(rApt + ks * 64), ld16(w2b + ((ks * 64 + q * 16) ^ sw)), b0);
      b1 = mfma16(ld16(rApt + ks * 64 + 64), ld16(w2b + ((ks * 64 + 64 + q * 16) ^ sw)), b1);
    }
    f32x4 c2 = b0 + b1;
    if (n < 8) {
#pragma unroll
      for (int r = 0; r < 4; ++r) {
        float th = tanh_fast(c2[r] + x2[r]);
        float hn = hf[r] + zz[r] * (th - hf[r]);
        hf[r] = hn;
        hbf[(m0 + r) * 1024 + jcol] = __float2bfloat16(hn);
        out[((size_t)t * 64 + m0 + r) * 1024 + jcol] = hn;
      }
    }
    grid_bar(cnt, rel, bi++, g);
  }
}

// --------------------------- host launch -----------------------------------
extern "C" void kernel_launch(void* const* d_in, const int* in_sizes, int n_in,
                              void* d_out, int out_size, void* d_ws, size_t ws_size,
                              hipStream_t stream) {
  if (ws_size < WS_NEED) return;  // fail loudly via validation
  const float* x    = (const float*)d_in[0];
  const float* Wfc  = (const float*)d_in[1];
  const float* Wfc2 = (const float*)d_in[2];
  float* out = (float*)d_out;
  char* ws = (char*)d_ws;

  __hip_bfloat16* xall = (__hip_bfloat16*)(ws + XALL_OFF);
  __hip_bfloat16* Wxp  = (__hip_bfloat16*)(ws + WXP_OFF);
  __hip_bfloat16* hbf  = (__hip_bfloat16*)(ws + HBF_OFF);
  __hip_bfloat16* rhb  = (__hip_bfloat16*)(ws + RH_OFF);
  int* bar             = (int*)(ws + BAR_OFF);
  __hip_bfloat16* Xbf  = (__hip_bfloat16*)d_out;  // dead storage until recurrent

  cvt_x<<<32768, 256, 0, stream>>>(x, Xbf);                       // X -> bf16
  pack_w<<<3072, 256, 0, stream>>>(Wfc, Wfc2, Wxp);               // pack x-part weights
  init_k<<<64, 256, 0, stream>>>(hbf, bar);                       // h0, barrier
  gemm_xw<<<dim3(24, 256), 256, 0, stream>>>(Xbf, Wxp, xall);     // X @ Wx^T

  void* args[] = {(void*)&Wfc, (void*)&Wfc2, (void*)&xall, (void*)&hbf,
                  (void*)&rhb, (void*)&out, (void*)&bar};
  hipLaunchCooperativeKernel((void*)recurrent_k, dim3(NWG), dim3(256), args, 0, stream);
}